// Round 3
// baseline (130.144 us; speedup 1.0000x reference)
//
#include <hip/hip_runtime.h>

// B = 4194304 rows, x is (B,4) fp32 row-major. Three 3->4->1 MLPs (relu ->
// sigmoid), output selected by sel = x[:,1] in {0,1,2}. Memory-bound:
// 64 MiB read + 16 MiB write = 80 MiB -> ~12.7us floor at 6.3 TB/s.
//
// R3 = R2 with the nontemporal builtins applied to a NATIVE vector type
// (clang ext_vector_type) — HIP's float4 is a class and the builtin rejects it.
//  - 4 rows per thread: 4x fewer waves, one dwordx4 store instead of 4 dwords.
//  - nontemporal (nt) loads/stores: streamed-once data, don't thrash L2.
//  - sigmoid via v_rcp_f32 (~1ulp; threshold 1.03e-2) instead of div sequence.

typedef float v4f __attribute__((ext_vector_type(4)));

__global__ __launch_bounds__(256) void Program_72902774882571_kernel(
    const v4f* __restrict__ x4,
    const float* __restrict__ Ws1, const float* __restrict__ bs1,
    const float* __restrict__ Ws2, const float* __restrict__ bs2,
    const float* __restrict__ Wu1, const float* __restrict__ bu1,
    const float* __restrict__ Wu2, const float* __restrict__ bu2,
    const float* __restrict__ Wd1, const float* __restrict__ bd1,
    const float* __restrict__ Wd2, const float* __restrict__ bd2,
    v4f* __restrict__ out4, int nvec)  // nvec = B/4
{
    int t = blockIdx.x * blockDim.x + threadIdx.x;
    if (t >= nvec) return;

    // 4 consecutive rows (each row is one float4 = 16B). The 4 unrolled
    // dwordx4 loads fully consume every fetched line.
    v4f rows[4];
#pragma unroll
    for (int r = 0; r < 4; ++r)
        rows[r] = __builtin_nontemporal_load(&x4[t * 4 + r]);

    // Weight pointers are kernel args (wave-uniform, constant indices) ->
    // s_load into SGPRs, hoisted; free inline operands to the v_fma chain.
    auto net = [](float x0, float x1, float x2,
                  const float* __restrict__ W1, const float* __restrict__ b1,
                  const float* __restrict__ W2, const float* __restrict__ b2) -> float {
        float acc = b2[0];
#pragma unroll
        for (int j = 0; j < 4; ++j) {
            float h = b1[j];
            h = fmaf(x0, W1[0 * 4 + j], h);
            h = fmaf(x1, W1[1 * 4 + j], h);
            h = fmaf(x2, W1[2 * 4 + j], h);
            h = fmaxf(h, 0.0f);              // relu
            acc = fmaf(h, W2[j], acc);
        }
        // sigmoid: v_exp_f32 + v_rcp_f32 (both ~1-2 ulp; threshold 1.03e-2)
        return __builtin_amdgcn_rcpf(1.0f + __expf(-acc));
    };

    float res[4];
#pragma unroll
    for (int r = 0; r < 4; ++r) {
        const float x0 = rows[r].x, x1 = rows[r].y, x2 = rows[r].z;
        const float os = net(x0, x1, x2, Ws1, bs1, Ws2, bs2);
        const float ou = net(x0, x1, x2, Wu1, bu1, Wu2, bu2);
        const float od = net(x0, x1, x2, Wd1, bd1, Wd2, bd2);
        float v = (x1 == 2.0f) ? od : 0.0f;   // sel in {0,1,2}; else 0
        v = (x1 == 1.0f) ? ou : v;
        v = (x1 == 0.0f) ? os : v;
        res[r] = v;
    }

    v4f o = { res[0], res[1], res[2], res[3] };
    __builtin_nontemporal_store(o, &out4[t]);  // dwordx4 nt, coalesced
}

extern "C" void kernel_launch(void* const* d_in, const int* in_sizes, int n_in,
                              void* d_out, int out_size, void* d_ws, size_t ws_size,
                              hipStream_t stream) {
    const v4f* x4    = (const v4f*)d_in[0];
    const float* Ws1 = (const float*)d_in[1];
    const float* bs1 = (const float*)d_in[2];
    const float* Ws2 = (const float*)d_in[3];
    const float* bs2 = (const float*)d_in[4];
    const float* Wu1 = (const float*)d_in[5];
    const float* bu1 = (const float*)d_in[6];
    const float* Wu2 = (const float*)d_in[7];
    const float* bu2 = (const float*)d_in[8];
    const float* Wd1 = (const float*)d_in[9];
    const float* bd1 = (const float*)d_in[10];
    const float* Wd2 = (const float*)d_in[11];
    const float* bd2 = (const float*)d_in[12];

    const int n = out_size;          // B = 4194304, divisible by 4
    const int nvec = n / 4;          // 1048576 threads
    const int block = 256;
    const int grid = (nvec + block - 1) / block;  // 4096 blocks

    Program_72902774882571_kernel<<<grid, block, 0, stream>>>(
        x4, Ws1, bs1, Ws2, bs2, Wu1, bu1, Wu2, bu2, Wd1, bd1, Wd2, bd2,
        (v4f*)d_out, nvec);
}